// Round 1
// baseline (95.552 us; speedup 1.0000x reference)
//
#include <hip/hip_runtime.h>

// S4D SSKernelDiag forward: K[h,l] = 2*Re( sum_n C_eff[h,n] * dA[h,n]^l )
// H=1024, N=32 (half state), L=4096, C=1. Output (1,H,L) fp32 = 16 MB.
//
// Strategy: one block per h. Setup (first 32 threads) computes dA, C_eff and
// LDS power tables dA^t (t<16), dA^(16t) (t<16), dA^256. Main loop: thread tid
// handles l = tid + 256*j for j=0..15; start power via one complex mul from
// the two tables, then recurrence p *= dA^256. Multiply-chain depth <= ~60
// => rel err ~3e-5, far under threshold. All-register accumulators,
// coalesced stores, LDS reads are broadcast/2-way (free on gfx950).

#define HDIM    1024
#define NSTATE  32
#define SEQ_L   4096
#define TPB     256
#define JCOUNT  (SEQ_L / TPB)   // 16

__global__ __launch_bounds__(TPB) void sskernel_diag(
    const float* __restrict__ log_dt,      // (H,)
    const float* __restrict__ B_ri,        // (H, N, 2)
    const float* __restrict__ C_ri,        // (1, H, N, 2)
    const float* __restrict__ inv_A_real,  // (H, N)
    const float* __restrict__ A_imag,      // (H, N)
    float* __restrict__ out)               // (1, H, L)
{
    __shared__ float2 s_lo[NSTATE][16];   // dA^t,      t = 0..15
    __shared__ float2 s_hi[NSTATE][16];   // dA^(16t),  t = 0..15
    __shared__ float2 s_step[NSTATE];     // dA^256
    __shared__ float2 s_ceff[NSTATE];     // 2*dt*B*C/(1-dtA/2)

    const int h   = blockIdx.x;
    const int tid = threadIdx.x;

    if (tid < NSTATE) {
        const int n   = tid;
        const int idx = h * NSTATE + n;

        const float dt   = expf(log_dt[h]);
        const float Ar   = -expf(inv_A_real[idx]);
        const float Ai   = A_imag[idx];
        const float dtAr = Ar * dt;
        const float dtAi = Ai * dt;

        // denom = 1 - dtA/2 ; numer = 1 + dtA/2
        const float dr = 1.0f - 0.5f * dtAr;
        const float di =       -0.5f * dtAi;
        const float nr = 1.0f + 0.5f * dtAr;
        const float ni =        0.5f * dtAi;
        const float inv_den = 1.0f / (dr * dr + di * di);

        // dA = numer * conj(denom) / |denom|^2   (|dA| < 1 since Re(dtA) < 0)
        const float dAr = (nr * dr + ni * di) * inv_den;
        const float dAi = (ni * dr - nr * di) * inv_den;

        // C_eff = 2 * dt * (B*C) * conj(denom) / |denom|^2
        const float br = B_ri[2 * idx], bi = B_ri[2 * idx + 1];
        const float cr = C_ri[2 * idx], ci = C_ri[2 * idx + 1];
        const float bcr = br * cr - bi * ci;
        const float bci = br * ci + bi * cr;
        const float scale = 2.0f * dt * inv_den;
        s_ceff[n] = make_float2((bcr * dr + bci * di) * scale,
                                (bci * dr - bcr * di) * scale);

        // low table: dA^0 .. dA^15 ; after loop (pr,pi) = dA^16
        float pr = 1.0f, pi = 0.0f;
        #pragma unroll
        for (int t = 0; t < 16; ++t) {
            s_lo[n][t] = make_float2(pr, pi);
            const float tr = pr * dAr - pi * dAi;
            pi = pr * dAi + pi * dAr;
            pr = tr;
        }
        const float g16r = pr, g16i = pi;   // dA^16

        // high table: dA^0, dA^16, .. dA^240 ; after loop (qr,qi) = dA^256
        float qr = 1.0f, qi = 0.0f;
        #pragma unroll
        for (int t = 0; t < 16; ++t) {
            s_hi[n][t] = make_float2(qr, qi);
            const float tr = qr * g16r - qi * g16i;
            qi = qr * g16i + qi * g16r;
            qr = tr;
        }
        s_step[n] = make_float2(qr, qi);    // dA^256
    }
    __syncthreads();

    float acc[JCOUNT];
    #pragma unroll
    for (int j = 0; j < JCOUNT; ++j) acc[j] = 0.0f;

    const int i_lo = tid & 15;
    const int i_hi = tid >> 4;

    #pragma unroll 4
    for (int n = 0; n < NSTATE; ++n) {
        const float2 lo = s_lo[n][i_lo];
        const float2 hi = s_hi[n][i_hi];
        const float2 st = s_step[n];
        const float2 ce = s_ceff[n];

        // p = dA^tid
        float pr = lo.x * hi.x - lo.y * hi.y;
        float pi = lo.x * hi.y + lo.y * hi.x;

        #pragma unroll
        for (int j = 0; j < JCOUNT; ++j) {
            acc[j] += ce.x * pr - ce.y * pi;     // += Re(C_eff * p)
            const float tr = pr * st.x - pi * st.y;
            pi = pr * st.y + pi * st.x;          // p *= dA^256
            pr = tr;
        }
    }

    float* o = out + (size_t)h * SEQ_L + tid;
    #pragma unroll
    for (int j = 0; j < JCOUNT; ++j) o[j * TPB] = acc[j];
}

extern "C" void kernel_launch(void* const* d_in, const int* in_sizes, int n_in,
                              void* d_out, int out_size, void* d_ws, size_t ws_size,
                              hipStream_t stream) {
    const float* log_dt     = (const float*)d_in[0];
    const float* B_ri       = (const float*)d_in[1];
    const float* C_ri       = (const float*)d_in[2];
    const float* inv_A_real = (const float*)d_in[3];
    const float* A_imag     = (const float*)d_in[4];
    float* out = (float*)d_out;

    sskernel_diag<<<HDIM, TPB, 0, stream>>>(log_dt, B_ri, C_ri,
                                            inv_A_real, A_imag, out);
}

// Round 2
// 86.207 us; speedup vs baseline: 1.1084x; 1.1084x over previous
//
#include <hip/hip_runtime.h>

// S4D SSKernelDiag forward: K[h,l] = 2*Re( sum_n C_eff[h,n] * dA[h,n]^l )
// H=1024, N=32, L=4096, C=1. Output (1,H,L) fp32 = 16 MB.
//
// R1: replace per-element complex multiply (6 fma) with the real 2nd-order
// recurrence c_{j+1} = 2Re(dA^s) c_j - |dA^s|^2 c_{j-1}  (s = 256), which is
// 3 VALU ops per (n,j). Split each h into 2 blocks (L halves) -> 2048 blocks
// = 8 blocks/CU = full 32 waves/CU occupancy. Roots are inside the unit
// circle so the recurrence is numerically stable; chain depth ~8 steps.

#define HDIM    1024
#define NSTATE  32
#define SEQ_L   4096
#define TPB     256
#define LSPLIT  2                     // blocks per h
#define LCHUNK  (SEQ_L / LSPLIT)      // 2048
#define JCOUNT  (LCHUNK / TPB)        // 8

__global__ __launch_bounds__(TPB) void sskernel_diag(
    const float* __restrict__ log_dt,      // (H,)
    const float* __restrict__ B_ri,        // (H, N, 2)
    const float* __restrict__ C_ri,        // (1, H, N, 2)
    const float* __restrict__ inv_A_real,  // (H, N)
    const float* __restrict__ A_imag,      // (H, N)
    float* __restrict__ out)               // (1, H, L)
{
    __shared__ float2 s_lo[NSTATE][16];   // dA^t,      t = 0..15
    __shared__ float2 s_hi[NSTATE][16];   // dA^(16t),  t = 0..15
    __shared__ float2 s_rec[NSTATE];      // (2*Re(dA^256), -|dA^256|^2)
    __shared__ float2 s_ceA[NSTATE];      // C_eff * dA^(2048*half)
    __shared__ float2 s_ceB[NSTATE];      // ceA * dA^256

    const int h    = blockIdx.x >> 1;
    const int half = blockIdx.x & 1;
    const int tid  = threadIdx.x;

    if (tid < NSTATE) {
        const int n   = tid;
        const int idx = h * NSTATE + n;

        const float dt   = expf(log_dt[h]);
        const float Ar   = -expf(inv_A_real[idx]);
        const float Ai   = A_imag[idx];
        const float dtAr = Ar * dt;
        const float dtAi = Ai * dt;

        // denom = 1 - dtA/2 ; numer = 1 + dtA/2
        const float dr = 1.0f - 0.5f * dtAr;
        const float di =       -0.5f * dtAi;
        const float nr = 1.0f + 0.5f * dtAr;
        const float ni =        0.5f * dtAi;
        const float inv_den = 1.0f / (dr * dr + di * di);

        // dA = numer * conj(denom) / |denom|^2   (|dA| < 1)
        const float dAr = (nr * dr + ni * di) * inv_den;
        const float dAi = (ni * dr - nr * di) * inv_den;

        // C_eff (incl. the factor 2): 2*dt*(B*C)*conj(denom)/|denom|^2
        const float br = B_ri[2 * idx], bi = B_ri[2 * idx + 1];
        const float cr = C_ri[2 * idx], ci = C_ri[2 * idx + 1];
        const float bcr = br * cr - bi * ci;
        const float bci = br * ci + bi * cr;
        const float scale = 2.0f * dt * inv_den;
        float cer = (bcr * dr + bci * di) * scale;
        float cei = (bci * dr - bcr * di) * scale;

        // low table: dA^0 .. dA^15 ; exits with (pr,pi) = dA^16
        float pr = 1.0f, pi = 0.0f;
        #pragma unroll
        for (int t = 0; t < 16; ++t) {
            s_lo[n][t] = make_float2(pr, pi);
            const float tr = pr * dAr - pi * dAi;
            pi = pr * dAi + pi * dAr;
            pr = tr;
        }
        const float g16r = pr, g16i = pi;

        // high table: (dA^16)^t, t=0..15 ; exits with (qr,qi) = dA^256
        float qr = 1.0f, qi = 0.0f;
        #pragma unroll
        for (int t = 0; t < 16; ++t) {
            s_hi[n][t] = make_float2(qr, qi);
            const float tr = qr * g16r - qi * g16i;
            qi = qr * g16i + qi * g16r;
            qr = tr;
        }
        // recurrence coeffs for step s=256
        s_rec[n] = make_float2(2.0f * qr, -(qr * qr + qi * qi));

        if (half) {
            // g2048 = (dA^256)^8 via 3 squarings
            float rr = qr, ri = qi;
            #pragma unroll
            for (int t = 0; t < 3; ++t) {
                const float tr = rr * rr - ri * ri;
                ri = 2.0f * rr * ri;
                rr = tr;
            }
            const float tr = cer * rr - cei * ri;
            cei = cer * ri + cei * rr;
            cer = tr;
        }
        s_ceA[n] = make_float2(cer, cei);
        s_ceB[n] = make_float2(cer * qr - cei * qi, cer * qi + cei * qr);
    }
    __syncthreads();

    float acc[JCOUNT];
    #pragma unroll
    for (int j = 0; j < JCOUNT; ++j) acc[j] = 0.0f;

    const int i_lo = tid & 15;
    const int i_hi = tid >> 4;

    #pragma unroll 4
    for (int n = 0; n < NSTATE; ++n) {
        const float2 lo  = s_lo[n][i_lo];
        const float2 hi  = s_hi[n][i_hi];
        const float2 ceA = s_ceA[n];
        const float2 ceB = s_ceB[n];
        const float2 rec = s_rec[n];

        // p = dA^tid
        const float pr = lo.x * hi.x - lo.y * hi.y;
        const float pi = lo.x * hi.y + lo.y * hi.x;

        float c0 = ceA.x * pr - ceA.y * pi;   // Re(ceA * p)  -> j=0
        float c1 = ceB.x * pr - ceB.y * pi;   // Re(ceB * p)  -> j=1
        acc[0] += c0;
        acc[1] += c1;

        #pragma unroll
        for (int j = 2; j < JCOUNT; ++j) {
            const float c2 = rec.x * c1 + rec.y * c0;
            acc[j] += c2;
            c0 = c1;
            c1 = c2;
        }
    }

    float* o = out + (size_t)h * SEQ_L + half * LCHUNK + tid;
    #pragma unroll
    for (int j = 0; j < JCOUNT; ++j) o[j * TPB] = acc[j];
}

extern "C" void kernel_launch(void* const* d_in, const int* in_sizes, int n_in,
                              void* d_out, int out_size, void* d_ws, size_t ws_size,
                              hipStream_t stream) {
    const float* log_dt     = (const float*)d_in[0];
    const float* B_ri       = (const float*)d_in[1];
    const float* C_ri       = (const float*)d_in[2];
    const float* inv_A_real = (const float*)d_in[3];
    const float* A_imag     = (const float*)d_in[4];
    float* out = (float*)d_out;

    sskernel_diag<<<HDIM * LSPLIT, TPB, 0, stream>>>(log_dt, B_ri, C_ri,
                                                     inv_A_real, A_imag, out);
}

// Round 3
// 84.721 us; speedup vs baseline: 1.1278x; 1.0175x over previous
//
#include <hip/hip_runtime.h>

// S4D SSKernelDiag forward: K[h,l] = 2*Re( sum_n C_eff[h,n] * dA[h,n]^l )
// H=1024, N=32, L=4096, C=1. Output (1,H,L) fp32 = 16 MB.
//
// R2 post-mortem: kernel was DS-pipe-bound (5 ds_read_b64 per thread per n,
// shared per-CU LDS pipe ~13 us) not VALU-bound (~6 us). R3:
//  - premultiply C_eff into the low power table (loA_t = C_eff*dA^t): start
//    values become 2-op real dots, no complex p.
//  - pack LDS to 2x ds_read_b128 per (thread,n): [loA | rec] and
//    [dA^(16u) | dA^(16u+256)].
//  - JCOUNT=16, grid=1024 (one block per h) to amortize reads: per-CU DS
//    ~5.1 us, VALU ~5.7 us, overlapped -> ~7 us kernel.
//  - setup split across 64 threads (2 roles/n), powers via squarings.
// Recurrence c_{j+1} = 2Re(dA^256) c_j - |dA^256|^2 c_{j-1}; roots inside
// unit circle -> stable.

#define HDIM    1024
#define NSTATE  32
#define SEQ_L   4096
#define TPB     256
#define JCOUNT  (SEQ_L / TPB)   // 16

__global__ __launch_bounds__(TPB) void sskernel_diag(
    const float* __restrict__ log_dt,      // (H,)
    const float* __restrict__ B_ri,        // (H, N, 2)
    const float* __restrict__ C_ri,        // (1, H, N, 2)
    const float* __restrict__ inv_A_real,  // (H, N)
    const float* __restrict__ A_imag,      // (H, N)
    float* __restrict__ out)               // (1, H, L)
{
    __shared__ float4 s_loR[NSTATE][16];  // (Ceff*dA^t).re/.im, rec.x, rec.y
    __shared__ float4 s_hh[NSTATE][16];   // dA^(16u).re/.im, dA^(16u+256).re/.im

    const int h   = blockIdx.x;
    const int tid = threadIdx.x;

    if (tid < 2 * NSTATE) {
        const int n    = tid & (NSTATE - 1);
        const int role = tid >> 5;           // 0: loR table, 1: hh table
        const int idx  = h * NSTATE + n;

        const float dt   = expf(log_dt[h]);
        const float Ar   = -expf(inv_A_real[idx]);
        const float Ai   = A_imag[idx];
        const float dtAr = Ar * dt;
        const float dtAi = Ai * dt;

        // denom = 1 - dtA/2 ; numer = 1 + dtA/2
        const float dr = 1.0f - 0.5f * dtAr;
        const float di =       -0.5f * dtAi;
        const float inv_den = 1.0f / (dr * dr + di * di);

        // dA = numer * conj(denom) / |denom|^2   (|dA| < 1)
        const float nr = 1.0f + 0.5f * dtAr;
        const float ni =        0.5f * dtAi;
        const float dAr = (nr * dr + ni * di) * inv_den;
        const float dAi = (ni * dr - nr * di) * inv_den;

        if (role == 0) {
            // dA^256 via 8 squarings -> recurrence coeffs
            float sr = dAr, si = dAi;
            #pragma unroll
            for (int t = 0; t < 8; ++t) {
                const float tr = sr * sr - si * si;
                si = 2.0f * sr * si;
                sr = tr;
            }
            const float recx = 2.0f * sr;
            const float recy = -(sr * sr + si * si);

            // C_eff (incl. factor 2): 2*dt*(B*C)*conj(denom)/|denom|^2
            const float br = B_ri[2 * idx], bi = B_ri[2 * idx + 1];
            const float cr = C_ri[2 * idx], ci = C_ri[2 * idx + 1];
            const float bcr = br * cr - bi * ci;
            const float bci = br * ci + bi * cr;
            const float scale = 2.0f * dt * inv_den;
            float pr = (bcr * dr + bci * di) * scale;
            float pi = (bci * dr - bcr * di) * scale;

            // loR[t] = (Ceff*dA^t, rec)
            #pragma unroll
            for (int t = 0; t < 16; ++t) {
                s_loR[n][t] = make_float4(pr, pi, recx, recy);
                const float tr = pr * dAr - pi * dAi;
                pi = pr * dAi + pi * dAr;
                pr = tr;
            }
        } else {
            // e16 = dA^16 (4 squarings), s = dA^256 (4 more)
            float er = dAr, ei = dAi;
            #pragma unroll
            for (int t = 0; t < 4; ++t) {
                const float tr = er * er - ei * ei;
                ei = 2.0f * er * ei;
                er = tr;
            }
            float sr = er, si = ei;
            #pragma unroll
            for (int t = 0; t < 4; ++t) {
                const float tr = sr * sr - si * si;
                si = 2.0f * sr * si;
                sr = tr;
            }
            // hh[u] = (dA^(16u), dA^(16u)*dA^256)
            float qr = 1.0f, qi = 0.0f;
            #pragma unroll
            for (int u = 0; u < 16; ++u) {
                s_hh[n][u] = make_float4(qr, qi,
                                         qr * sr - qi * si,
                                         qr * si + qi * sr);
                const float tr = qr * er - qi * ei;
                qi = qr * ei + qi * er;
                qr = tr;
            }
        }
    }
    __syncthreads();

    float acc[JCOUNT];
    #pragma unroll
    for (int j = 0; j < JCOUNT; ++j) acc[j] = 0.0f;

    const int i_lo = tid & 15;
    const int i_hi = tid >> 4;

    #pragma unroll 4
    for (int n = 0; n < NSTATE; ++n) {
        const float4 LR = s_loR[n][i_lo];   // loA.re, loA.im, rec.x, rec.y
        const float4 HH = s_hh[n][i_hi];    // g.re, g.im, g2.re, g2.im

        float c0 = LR.x * HH.x - LR.y * HH.y;   // Re(loA * g)     -> j=0
        float c1 = LR.x * HH.z - LR.y * HH.w;   // Re(loA * g*s)   -> j=1
        acc[0] += c0;
        acc[1] += c1;

        #pragma unroll
        for (int j = 2; j < JCOUNT; ++j) {
            const float c2 = LR.z * c1 + LR.w * c0;
            acc[j] += c2;
            c0 = c1;
            c1 = c2;
        }
    }

    float* o = out + (size_t)h * SEQ_L + tid;
    #pragma unroll
    for (int j = 0; j < JCOUNT; ++j) o[j * TPB] = acc[j];
}

extern "C" void kernel_launch(void* const* d_in, const int* in_sizes, int n_in,
                              void* d_out, int out_size, void* d_ws, size_t ws_size,
                              hipStream_t stream) {
    const float* log_dt     = (const float*)d_in[0];
    const float* B_ri       = (const float*)d_in[1];
    const float* C_ri       = (const float*)d_in[2];
    const float* inv_A_real = (const float*)d_in[3];
    const float* A_imag     = (const float*)d_in[4];
    float* out = (float*)d_out;

    sskernel_diag<<<HDIM, TPB, 0, stream>>>(log_dt, B_ri, C_ri,
                                            inv_A_real, A_imag, out);
}